// Round 6
// baseline (175.946 us; speedup 1.0000x reference)
//
#include <hip/hip_runtime.h>
#include <math.h>

// PBC neighbor-list distances + per-cutoff masks, store-bandwidth-bound.
//
// Output layout (float32): [ d2[P] | mask0[P] | mask1[P] ... ]
//   P  = Pc + S*n*n,  Pc = n*(n-1)/2
//   p < Pc               : in-cell triu pair, row-major (i<j)
//   p = Pc + s*n*n+i*n+j : shifted-image pair (s,i,j)
// Masks written as float 0.0/1.0.
//
// R6 structure: ONE OUTPUT STREAM PER BLOCK. grid (1, n, (S+1)*(NCUT+1)):
//   z -> (sg, s): sg = z/(S+1) selects the stream (0=d2, c=mask[c-1]),
//                 s  = z%(S+1) selects shift slice (s==S -> triangular).
// Distances are recomputed per stream — f64 VALU issue rate is ~5x under
// the store floor, so 3x recompute is free; in exchange every wave writes
// one contiguous run and consecutive blocks sweep each 54 MB stream
// sequentially (fill-shaped traffic, the pattern that measures 6.6 TB/s).
//
// Distance math in f64 to match the numpy-f64 validator exactly at the
// mask boundary (d2 < cutoff^2); d2's own threshold is loose (bf16-level).

typedef float f32x4 __attribute__((ext_vector_type(4)));

template <int NCUT>
__global__ void __launch_bounds__(256) nbr_split(
    const float* __restrict__ pos,
    const float* __restrict__ cell,
    const float* __restrict__ shifts,
    const float* __restrict__ cutoffs,
    int n, int S,
    float* __restrict__ out, unsigned P, unsigned Pc)
{
    const int tid = threadIdx.x;
    const int z   = blockIdx.z;
    const int sg  = z / (S + 1);        // 0 = d2, 1..NCUT = mask[sg-1]
    const int s   = z - sg * (S + 1);   // shift slice; s==S -> triangular

    double cut2 = 0.0;
    if (sg > 0) { double cv = (double)cutoffs[sg - 1]; cut2 = cv * cv; }

    f32x4 v;

    if (s < S) {
        // ---------------- shifted-image region ----------------
        const unsigned j0 = (unsigned)tid << 2;
        if (j0 >= (unsigned)n) return;
        const unsigned i = blockIdx.y;

        // wave-uniform setup (scalar loads + once-per-wave f64)
        double s0 = (double)shifts[3*s+0], s1 = (double)shifts[3*s+1], s2 = (double)shifts[3*s+2];
        double sv0 = s0 * (double)cell[0] + s1 * (double)cell[3] + s2 * (double)cell[6];
        double sv1 = s0 * (double)cell[1] + s1 * (double)cell[4] + s2 * (double)cell[7];
        double sv2 = s0 * (double)cell[2] + s1 * (double)cell[5] + s2 * (double)cell[8];
        double pix = (double)pos[3*i+0];
        double piy = (double)pos[3*i+1];
        double piz = (double)pos[3*i+2];

        // 4 consecutive atoms j0..j0+3 = 12 floats, 16B-aligned (j0%4==0)
        const float4* pj = (const float4*)(pos + 3 * j0);
        float4 a = pj[0], b = pj[1], c4 = pj[2];
        float jx[4] = {a.x, a.w, b.z, c4.y};
        float jy[4] = {a.y, b.x, b.w, c4.z};
        float jz[4] = {a.z, b.y, c4.x, c4.w};

#pragma unroll
        for (int k = 0; k < 4; ++k) {
            double dx = (pix - (double)jx[k]) + sv0;
            double dy = (piy - (double)jy[k]) + sv1;
            double dz = (piz - (double)jz[k]) + sv2;
            double d2 = dx*dx + dy*dy + dz*dz;
            v[k] = (sg == 0) ? (float)d2 : ((d2 < cut2) ? 1.0f : 0.0f);
        }

        const unsigned t0 = ((unsigned)s * (unsigned)n + i) * (unsigned)n + j0 + Pc;
        *(f32x4*)(out + (unsigned)sg * P + t0) = v;
    } else {
        // ---------------- in-cell triangular region ----------------
        const unsigned p0 = ((blockIdx.y * 256u) + (unsigned)tid) << 2;
        if (p0 >= Pc) return;

        const long long tn = 2LL * n - 1;
#pragma unroll
        for (int k = 0; k < 4; ++k) {
            long long p = (long long)p0 + k;
            double D = (double)(tn * tn) - 8.0 * (double)p;
            long long i = (long long)(((double)tn - sqrt(D)) * 0.5);
            if (i < 0) i = 0;
            if (i > n - 2) i = n - 2;
            while ((i + 1) * (tn - (i + 1)) / 2 <= p) ++i;   // A(i+1) <= p
            while (i * (tn - i) / 2 > p) --i;                // A(i)   >  p
            long long j = p - i * (tn - i) / 2 + i + 1;

            double dx = (double)pos[3*i+0] - (double)pos[3*j+0];
            double dy = (double)pos[3*i+1] - (double)pos[3*j+1];
            double dz = (double)pos[3*i+2] - (double)pos[3*j+2];
            double d2 = dx*dx + dy*dy + dz*dz;
            v[k] = (sg == 0) ? (float)d2 : ((d2 < cut2) ? 1.0f : 0.0f);
        }

        *(f32x4*)(out + (unsigned)sg * P + p0) = v;
    }
}

// Generic scalar fallback (any n, any ncut) — unused at n=1000.
__global__ void __launch_bounds__(256) nbr_scalar(
    const float* __restrict__ pos,
    const float* __restrict__ cell,
    const float* __restrict__ shifts,
    const float* __restrict__ cutoffs,
    int ncut, int n,
    float* __restrict__ out, long long P, long long Pc)
{
    long long p = (long long)blockIdx.x * 256 + threadIdx.x;
    if (p >= P) return;

    double d2;
    if (p >= Pc) {
        long long q = p - Pc;
        unsigned long long nn = (unsigned long long)n * n;
        unsigned s = (unsigned)(q / nn);
        unsigned long long r = q - (unsigned long long)s * nn;
        unsigned i = (unsigned)(r / n);
        unsigned j = (unsigned)(r - (unsigned long long)i * n);
        double s0 = (double)shifts[3*s+0], s1 = (double)shifts[3*s+1], s2 = (double)shifts[3*s+2];
        double sv0 = s0*(double)cell[0] + s1*(double)cell[3] + s2*(double)cell[6];
        double sv1 = s0*(double)cell[1] + s1*(double)cell[4] + s2*(double)cell[7];
        double sv2 = s0*(double)cell[2] + s1*(double)cell[5] + s2*(double)cell[8];
        double dx = ((double)pos[3*i+0] - (double)pos[3*j+0]) + sv0;
        double dy = ((double)pos[3*i+1] - (double)pos[3*j+1]) + sv1;
        double dz = ((double)pos[3*i+2] - (double)pos[3*j+2]) + sv2;
        d2 = dx*dx + dy*dy + dz*dz;
    } else {
        long long tn = 2LL * n - 1;
        double D = (double)(tn * tn) - 8.0 * (double)p;
        long long i = (long long)(((double)tn - sqrt(D)) * 0.5);
        if (i < 0) i = 0;
        if (i > n - 2) i = n - 2;
        while ((i + 1) * (tn - (i + 1)) / 2 <= p) ++i;
        while (i * (tn - i) / 2 > p) --i;
        long long j = p - i * (tn - i) / 2 + i + 1;
        double dx = (double)pos[3*i+0] - (double)pos[3*j+0];
        double dy = (double)pos[3*i+1] - (double)pos[3*j+1];
        double dz = (double)pos[3*i+2] - (double)pos[3*j+2];
        d2 = dx*dx + dy*dy + dz*dz;
    }
    out[p] = (float)d2;
    for (int c = 0; c < ncut; ++c) {
        double cv = (double)cutoffs[c];
        out[(long long)(c + 1) * P + p] = (d2 < cv * cv) ? 1.0f : 0.0f;
    }
}

extern "C" void kernel_launch(void* const* d_in, const int* in_sizes, int n_in,
                              void* d_out, int out_size, void* d_ws, size_t ws_size,
                              hipStream_t stream)
{
    const float* pos     = (const float*)d_in[0];
    const float* cell    = (const float*)d_in[1];
    const float* shifts  = (const float*)d_in[2];
    const float* cutoffs = (const float*)d_in[3];
    int n    = in_sizes[0] / 3;   // 1000
    int S    = in_sizes[2] / 3;   // 13
    int ncut = in_sizes[3];       // 2

    long long Pc = (long long)n * (n - 1) / 2;          // 499500
    long long P  = Pc + (long long)S * n * n;           // 13499500
    float* out = (float*)d_out;

    bool fast = ((n & 3) == 0) && (n <= 2049) && (ncut >= 1) && (ncut <= 4) &&
                (3 * P < (1LL << 31));
    if (fast) {
        dim3 grid(1, n, (S + 1) * (ncut + 1));
        unsigned uP = (unsigned)P, uPc = (unsigned)Pc;
        switch (ncut) {
        case 1: nbr_split<1><<<grid, 256, 0, stream>>>(pos, cell, shifts, cutoffs, n, S, out, uP, uPc); break;
        case 2: nbr_split<2><<<grid, 256, 0, stream>>>(pos, cell, shifts, cutoffs, n, S, out, uP, uPc); break;
        case 3: nbr_split<3><<<grid, 256, 0, stream>>>(pos, cell, shifts, cutoffs, n, S, out, uP, uPc); break;
        default: nbr_split<4><<<grid, 256, 0, stream>>>(pos, cell, shifts, cutoffs, n, S, out, uP, uPc); break;
        }
    } else {
        int blocks = (int)((P + 255) / 256);
        nbr_scalar<<<blocks, 256, 0, stream>>>(pos, cell, shifts, cutoffs,
                                               ncut, n, out, P, Pc);
    }
}

// Round 7
// 171.171 us; speedup vs baseline: 1.0279x; 1.0279x over previous
//
#include <hip/hip_runtime.h>
#include <math.h>

// PBC neighbor-list distances + per-cutoff masks, store-bandwidth-bound.
//
// Output layout (float32): [ d2[P] | mask0[P] | mask1[P] ... ]
//   P  = Pc + S*n*n,  Pc = n*(n-1)/2
//   p < Pc               : in-cell triu pair, row-major (i<j)
//   p = Pc + s*n*n+i*n+j : shifted-image pair (s,i,j)
// Masks written as float 0.0/1.0.
//
// R7 structure: PERSISTENT GRID-STRIDE (fill-shaped). 2048 blocks x 256
// threads = exactly one full residency (8 blocks/CU at this VGPR count);
// each thread loops ~6.4 chunks of 4 consecutive output elements, storing
// f32x4 to all three streams (d2, mask0, mask1). In the linear chunk
// mapping the shifted-region store index IS p0 (Pc + s*nn + i*n + j0 = p0),
// so addressing is trivial and each wave emits contiguous 1 KB runs.
// Prior rounds showed: per-lane vs uniform setup, NT vs cached stores,
// split vs interleaved streams, 13K vs 42K one-shot blocks — all neutral.
// This round tests one-shot vs persistent.
//
// Distance math in f64 to match the numpy-f64 validator exactly at the
// mask boundary (d2 < cutoff^2); d2's own threshold is loose (bf16-level).

typedef float f32x4 __attribute__((ext_vector_type(4)));

template <int NCUT>
__global__ void __launch_bounds__(256) nbr_stride(
    const float* __restrict__ pos,
    const float* __restrict__ cell,
    const float* __restrict__ shifts,
    const float* __restrict__ cutoffs,
    int n, int S,
    float* __restrict__ out, unsigned P, unsigned Pc)
{
    const unsigned Cs     = P >> 2;                       // total 16B chunks
    const unsigned Ct     = Pc >> 2;                      // triangular chunks
    const unsigned stride = gridDim.x * blockDim.x;
    unsigned u = blockIdx.x * blockDim.x + threadIdx.x;

    // loop-invariant setup (all wave-uniform)
    const double c00 = cell[0], c01 = cell[1], c02 = cell[2];
    const double c10 = cell[3], c11 = cell[4], c12 = cell[5];
    const double c20 = cell[6], c21 = cell[7], c22 = cell[8];
    double cut2[NCUT];
#pragma unroll
    for (int c = 0; c < NCUT; ++c) {
        double cv = (double)cutoffs[c];
        cut2[c] = cv * cv;
    }
    const unsigned un = (unsigned)n;
    const unsigned nn = un * un;
    const long long tn = 2LL * n - 1;

    for (; u < Cs; u += stride) {
        const unsigned p0 = u << 2;
        f32x4 d2v;
        f32x4 mv[NCUT];

        if (u >= Ct) {
            // ---------------- shifted-image region ----------------
            // q%4==0, nn%4==0, n%4==0 -> j0%4==0 (aligned float4 pos loads,
            // chunk never crosses an (s,i) row).
            const unsigned q  = p0 - Pc;
            const unsigned s  = q / nn;
            const unsigned r  = q - s * nn;
            const unsigned i  = r / un;
            const unsigned j0 = r - i * un;

            const double s0 = (double)shifts[3*s+0];
            const double s1 = (double)shifts[3*s+1];
            const double s2 = (double)shifts[3*s+2];
            const double sv0 = s0 * c00 + s1 * c10 + s2 * c20;
            const double sv1 = s0 * c01 + s1 * c11 + s2 * c21;
            const double sv2 = s0 * c02 + s1 * c12 + s2 * c22;
            const double pix = (double)pos[3*i+0];
            const double piy = (double)pos[3*i+1];
            const double piz = (double)pos[3*i+2];

            const float4* pj = (const float4*)(pos + 3 * j0);
            float4 a = pj[0], b = pj[1], c4 = pj[2];
            float jx[4] = {a.x, a.w, b.z, c4.y};
            float jy[4] = {a.y, b.x, b.w, c4.z};
            float jz[4] = {a.z, b.y, c4.x, c4.w};

#pragma unroll
            for (int k = 0; k < 4; ++k) {
                double dx = (pix - (double)jx[k]) + sv0;
                double dy = (piy - (double)jy[k]) + sv1;
                double dz = (piz - (double)jz[k]) + sv2;
                double d2 = dx*dx + dy*dy + dz*dz;
                d2v[k] = (float)d2;
#pragma unroll
                for (int c = 0; c < NCUT; ++c) mv[c][k] = (d2 < cut2[c]) ? 1.0f : 0.0f;
            }
        } else {
            // ---------------- in-cell triangular region ----------------
#pragma unroll
            for (int k = 0; k < 4; ++k) {
                long long p = (long long)p0 + k;
                double D = (double)(tn * tn) - 8.0 * (double)p;
                long long i = (long long)(((double)tn - sqrt(D)) * 0.5);
                if (i < 0) i = 0;
                if (i > n - 2) i = n - 2;
                while ((i + 1) * (tn - (i + 1)) / 2 <= p) ++i;   // A(i+1) <= p
                while (i * (tn - i) / 2 > p) --i;                // A(i)   >  p
                long long j = p - i * (tn - i) / 2 + i + 1;

                double dx = (double)pos[3*i+0] - (double)pos[3*j+0];
                double dy = (double)pos[3*i+1] - (double)pos[3*j+1];
                double dz = (double)pos[3*i+2] - (double)pos[3*j+2];
                double d2 = dx*dx + dy*dy + dz*dz;
                d2v[k] = (float)d2;
#pragma unroll
                for (int c = 0; c < NCUT; ++c) mv[c][k] = (d2 < cut2[c]) ? 1.0f : 0.0f;
            }
        }

        *(f32x4*)(out + p0) = d2v;                       // store index == p0
#pragma unroll
        for (int c = 0; c < NCUT; ++c)
            *(f32x4*)(out + (unsigned)(c + 1) * P + p0) = mv[c];
    }
}

// Generic scalar fallback (any n, any ncut) — unused at n=1000.
__global__ void __launch_bounds__(256) nbr_scalar(
    const float* __restrict__ pos,
    const float* __restrict__ cell,
    const float* __restrict__ shifts,
    const float* __restrict__ cutoffs,
    int ncut, int n,
    float* __restrict__ out, long long P, long long Pc)
{
    long long p = (long long)blockIdx.x * 256 + threadIdx.x;
    if (p >= P) return;

    double d2;
    if (p >= Pc) {
        long long q = p - Pc;
        unsigned long long nn = (unsigned long long)n * n;
        unsigned s = (unsigned)(q / nn);
        unsigned long long r = q - (unsigned long long)s * nn;
        unsigned i = (unsigned)(r / n);
        unsigned j = (unsigned)(r - (unsigned long long)i * n);
        double s0 = (double)shifts[3*s+0], s1 = (double)shifts[3*s+1], s2 = (double)shifts[3*s+2];
        double sv0 = s0*(double)cell[0] + s1*(double)cell[3] + s2*(double)cell[6];
        double sv1 = s0*(double)cell[1] + s1*(double)cell[4] + s2*(double)cell[7];
        double sv2 = s0*(double)cell[2] + s1*(double)cell[5] + s2*(double)cell[8];
        double dx = ((double)pos[3*i+0] - (double)pos[3*j+0]) + sv0;
        double dy = ((double)pos[3*i+1] - (double)pos[3*j+1]) + sv1;
        double dz = ((double)pos[3*i+2] - (double)pos[3*j+2]) + sv2;
        d2 = dx*dx + dy*dy + dz*dz;
    } else {
        long long tn = 2LL * n - 1;
        double D = (double)(tn * tn) - 8.0 * (double)p;
        long long i = (long long)(((double)tn - sqrt(D)) * 0.5);
        if (i < 0) i = 0;
        if (i > n - 2) i = n - 2;
        while ((i + 1) * (tn - (i + 1)) / 2 <= p) ++i;
        while (i * (tn - i) / 2 > p) --i;
        long long j = p - i * (tn - i) / 2 + i + 1;
        double dx = (double)pos[3*i+0] - (double)pos[3*j+0];
        double dy = (double)pos[3*i+1] - (double)pos[3*j+1];
        double dz = (double)pos[3*i+2] - (double)pos[3*j+2];
        d2 = dx*dx + dy*dy + dz*dz;
    }
    out[p] = (float)d2;
    for (int c = 0; c < ncut; ++c) {
        double cv = (double)cutoffs[c];
        out[(long long)(c + 1) * P + p] = (d2 < cv * cv) ? 1.0f : 0.0f;
    }
}

extern "C" void kernel_launch(void* const* d_in, const int* in_sizes, int n_in,
                              void* d_out, int out_size, void* d_ws, size_t ws_size,
                              hipStream_t stream)
{
    const float* pos     = (const float*)d_in[0];
    const float* cell    = (const float*)d_in[1];
    const float* shifts  = (const float*)d_in[2];
    const float* cutoffs = (const float*)d_in[3];
    int n    = in_sizes[0] / 3;   // 1000
    int S    = in_sizes[2] / 3;   // 13
    int ncut = in_sizes[3];       // 2

    long long Pc = (long long)n * (n - 1) / 2;          // 499500
    long long P  = Pc + (long long)S * n * n;           // 13499500
    float* out = (float*)d_out;

    bool fast = ((n & 3) == 0) && (ncut >= 1) && (ncut <= 4) &&
                (3 * P < (1LL << 31));
    if (fast) {
        long long chunks = P >> 2;                       // 3,374,875
        int blocks = 2048;                               // 8 blocks/CU, one residency
        long long need = (chunks + 255) / 256;
        if (need < blocks) blocks = (int)need;
        unsigned uP = (unsigned)P, uPc = (unsigned)Pc;
        switch (ncut) {
        case 1: nbr_stride<1><<<blocks, 256, 0, stream>>>(pos, cell, shifts, cutoffs, n, S, out, uP, uPc); break;
        case 2: nbr_stride<2><<<blocks, 256, 0, stream>>>(pos, cell, shifts, cutoffs, n, S, out, uP, uPc); break;
        case 3: nbr_stride<3><<<blocks, 256, 0, stream>>>(pos, cell, shifts, cutoffs, n, S, out, uP, uPc); break;
        default: nbr_stride<4><<<blocks, 256, 0, stream>>>(pos, cell, shifts, cutoffs, n, S, out, uP, uPc); break;
        }
    } else {
        int blocks = (int)((P + 255) / 256);
        nbr_scalar<<<blocks, 256, 0, stream>>>(pos, cell, shifts, cutoffs,
                                               ncut, n, out, P, Pc);
    }
}